// Round 6
// baseline (245.753 us; speedup 1.0000x reference)
//
#include <hip/hip_runtime.h>
#include <hip/hip_bf16.h>
#include <stdint.h>

#define HDIM 1024
#define FDIM 1024
#define TTOK 2048
#define CAP  2048
#define MSZ  (1024*1024)

typedef __attribute__((ext_vector_type(8))) __bf16 bf16x8;
typedef __attribute__((ext_vector_type(4))) float  f32x4;

static __device__ __forceinline__ unsigned short f2bf(float v) {
  unsigned int u = __float_as_uint(v);
  u += 0x7FFF + ((u >> 16) & 1);   // RNE
  return (unsigned short)(u >> 16);
}

static __device__ __forceinline__ unsigned pk2(float a, float b) {
  return (unsigned)f2bf(a) | ((unsigned)f2bf(b) << 16);
}

static __device__ __forceinline__ void gload_lds16(const void* g, void* l) {
  __builtin_amdgcn_global_load_lds(
      (const __attribute__((address_space(1))) unsigned int*)g,
      (__attribute__((address_space(3))) unsigned int*)l, 16, 0, 0);
}

// counts PADDED: counts[e<<4] (one 64B line per counter; unpadded = 4096
// serialized same-line RMWs ~35us, fixed in R4).

// ---------------- k_prep: router + x-cvt + weight transpose, ONE dispatch ----
// blocks 0..511: router; 512..1535: x cvt; 1536..4991: transpose tiles.
// Transpose tile now 128r x 64c (16 KB LDS): 8 blocks/CU resident (was 32KB ->
// ~2.4 blocks, latency-bound at 2.0 TB/s). LDS [128 rows][16 slots of 8B],
// phys_slot = (slot + 2*(row>>3)) & 15: stage-writes at structural minimum,
// gather ~4-way (gather phase is small).
__global__ __launch_bounds__(256) void k_prep(
    const float* __restrict__ x, const float* __restrict__ wg,
    const float* __restrict__ wgp, const float* __restrict__ wsg,
    const float* __restrict__ wup, const float* __restrict__ wsu,
    const float* __restrict__ wdp, const float* __restrict__ wsd,
    unsigned short* __restrict__ wB, unsigned short* __restrict__ xb,
    int* __restrict__ counts, int* __restrict__ tok_id, float* __restrict__ tok_w,
    int2* __restrict__ tsl, float* __restrict__ tw) {
  int b = blockIdx.x;
  int tid = threadIdx.x;
  if (b < 512) {
    // ---- router: wave per token, fp32, top2 + softmax + compaction ----
    int t = (b << 2) + (tid >> 6);
    int L = tid & 63;
    const float* xr = x + (size_t)t * HDIM;
    float acc[8] = {0, 0, 0, 0, 0, 0, 0, 0};
    for (int h = L; h < HDIM; h += 64) {
      float xv = xr[h];
      const float* wr = wg + h * 8;
      #pragma unroll
      for (int e = 0; e < 8; e++) acc[e] += xv * wr[e];
    }
    #pragma unroll
    for (int e = 0; e < 8; e++) {
      float v = acc[e];
      for (int off = 32; off > 0; off >>= 1) v += __shfl_xor(v, off);
      acc[e] = v;
    }
    if (L == 0) {
      int i1 = 0; float v1 = acc[0];
      #pragma unroll
      for (int e = 1; e < 8; e++) if (acc[e] > v1) { v1 = acc[e]; i1 = e; }
      int i2 = -1; float v2 = -1e30f;
      #pragma unroll
      for (int e = 0; e < 8; e++) if (e != i1 && acc[e] > v2) { v2 = acc[e]; i2 = e; }
      float ex = __expf(v2 - v1);
      float w1 = 1.f / (1.f + ex);
      float w2 = 1.f - w1;
      int p1 = atomicAdd(&counts[i1 << 4], 1);   // padded: 1 line per counter
      tok_id[i1 * CAP + p1] = t; tok_w[i1 * CAP + p1] = w1;
      int p2 = atomicAdd(&counts[i2 << 4], 1);
      tok_id[i2 * CAP + p2] = t; tok_w[i2 * CAP + p2] = w2;
      tsl[t] = make_int2((i1 << 10) + p1, (i2 << 10) + p2);  // y-row slots
      tw[t] = w1;
    }
  } else if (b < 1536) {
    // ---- x fp32 -> bf16 (8 elems/thread) ----
    int i = (b - 512) * 256 + tid;
    const float4* in4 = (const float4*)x;
    float4 f0 = in4[i * 2], f1 = in4[i * 2 + 1];
    uint4 v;
    v.x = pk2(f0.x, f0.y); v.y = pk2(f0.z, f0.w);
    v.z = pk2(f1.x, f1.y); v.w = pk2(f1.z, f1.w);
    *((uint4*)(xb + (size_t)i * 8)) = v;
    if (i < TTOK) { tok_id[8 * CAP + i] = i; tok_w[8 * CAP + i] = 1.0f; }
    if (i == 0) counts[8 << 4] = TTOK;
  } else {
    // ---- weight transpose + fp32->bf16, tile 128r x 64c ----
    int bt = b - 1536;                 // 0..3455
    int m = bt >> 7;                   // 0..26
    int idx = bt & 127;
    int rb = (idx >> 4) << 7;          // src row base (128 rows)
    int cb = (idx & 15) << 6;          // src col base (64 cols); b%16 groups
    const float* src;
    if (m < 8)       src = wgp + (size_t)m * MSZ;
    else if (m == 8) src = wsg;
    else if (m < 17) src = wup + (size_t)(m - 9) * MSZ;
    else if (m == 17) src = wsu;
    else if (m < 26) src = wdp + (size_t)(m - 18) * MSZ;
    else             src = wsd;
    unsigned short* dst = wB + (size_t)m * MSZ;
    __shared__ __align__(16) unsigned short T[128 * 64];   // 16 KiB bf16
    // ---- stage: contiguous global reads, rotation-swizzled LDS writes ----
    #pragma unroll
    for (int i = 0; i < 8; i++) {
      int g = tid + (i << 8);          // float4 index 0..2047
      int r = g >> 4;                  // src row 0..127 (16 f4 per row)
      int f4 = g & 15;                 // 16B chunk in row
      float4 v = *(const float4*)(src + (size_t)(rb + r) * 1024 + cb + (f4 << 2));
      uint2 p;
      p.x = pk2(v.x, v.y);
      p.y = pk2(v.z, v.w);
      int ps = (f4 + ((r >> 3) << 1)) & 15;   // rotated 8B slot
      *(uint2*)(T + r * 64 + (ps << 2)) = p;
    }
    __syncthreads();
    // ---- gather transposed: 8 u16 column reads -> 16B coalesced store ----
    int L = tid & 63, w = tid >> 6;
    int q = L & 15;                    // src-row group (dst 16B chunk)
    int cbase = (w << 2) + (L >> 4);   // dst row low bits
    #pragma unroll
    for (int j = 0; j < 4; j++) {
      int c = cbase + (j << 4);        // src col = dst row, 0..63
      int ps = ((c >> 2) + (q << 1)) & 15;
      const unsigned short* p = T + (q << 3) * 64 + (ps << 2) + (c & 3);
      unsigned short u0 = p[0],      u1 = p[64],      u2 = p[2 * 64],
                     u3 = p[3 * 64], u4 = p[4 * 64],  u5 = p[5 * 64],
                     u6 = p[6 * 64], u7 = p[7 * 64];
      uint4 o;
      o.x = (unsigned)u0 | ((unsigned)u1 << 16);
      o.y = (unsigned)u2 | ((unsigned)u3 << 16);
      o.z = (unsigned)u4 | ((unsigned)u5 << 16);
      o.w = (unsigned)u6 | ((unsigned)u7 << 16);
      *(uint4*)(dst + (size_t)(cb + c) * 1024 + rb + (q << 3)) = o;
    }
  }
}

// LDS tile layout (both GEMMs): row-major [row][64 bf16]; 16B chunk c of row R
// holds logical chunk c ^ (R&7) (conflict-free, verified earlier).
// 1D grids decoded so blocks sharing a B-tile have equal lin%8 -> same XCD.
// Both GEMMs 2-PHASE double-buffered; buffers statically named (rule #20).

// ---------------- GEMM1: act = silu(x@Wg) * (x@Wu), gathered rows ------------
// tile 128(M) x 32(N per output), BK=64; 4 waves 2x2 (wave = 64M x 16N).
// N=32: LDS 48KB -> 3 blocks/CU resident; 1536 active blocks = 6/CU = two
// EXACT rounds (was 768 active / 2 resident = 1.5 rounds, 33% tail idle).
__global__ __launch_bounds__(256, 3) void k_gemm1(
    const unsigned short* __restrict__ xb, const unsigned short* __restrict__ wB,
    const int* __restrict__ counts, const int* __restrict__ tok_id,
    unsigned short* __restrict__ actb) {
  int lin = blockIdx.x;
  int e = lin >> 9;
  int r9 = lin & 511;
  int nbi = (r9 & 7) | ((r9 >> 7) << 3);   // 0..31, constant mod-8 class per nb
  int mi  = (r9 >> 3) & 15;                // 0..15
  int Ne = (e == 8) ? TTOK : counts[e << 4];
  int rb = mi << 7;
  if (rb >= Ne) return;
  int nb = nbi << 5;
  const unsigned short* wgp_ = wB + (size_t)e * MSZ;        // [F][H] bf16
  const unsigned short* wup_ = wB + (size_t)(9 + e) * MSZ;  // [F][H] bf16
  __shared__ __align__(16) unsigned short As0[128 * 64];
  __shared__ __align__(16) unsigned short As1[128 * 64];
  __shared__ __align__(16) unsigned short Bg0[32 * 64];
  __shared__ __align__(16) unsigned short Bg1[32 * 64];
  __shared__ __align__(16) unsigned short Bu0[32 * 64];
  __shared__ __align__(16) unsigned short Bu1[32 * 64];
  int tid = threadIdx.x;
  int w = tid >> 6, L = tid & 63;
  int quad = L >> 4, lane15 = L & 15;
  int wr = w >> 1, wc = w & 1;
  int l7 = lane15 & 7;
  int sw8 = ((L & 7) ^ (L >> 3)) << 3;    // swizzled global chunk offset (elems)
  const int* tlist = tok_id + e * CAP + rb;
  int trow[4];
  #pragma unroll
  for (int r = 0; r < 4; r++) {
    int row = (w << 5) + (r << 3) + (L >> 3);
    trow[r] = (rb + row < Ne) ? tlist[row] : 0;
  }
  f32x4 accg[4], accu[4];
  #pragma unroll
  for (int mt = 0; mt < 4; mt++) {
    accg[mt] = (f32x4){0.f, 0.f, 0.f, 0.f};
    accu[mt] = (f32x4){0.f, 0.f, 0.f, 0.f};
  }
  auto stage = [&](unsigned short* As_, unsigned short* Bg_, unsigned short* Bu_,
                   int it) {
    int k0 = it << 6;
    #pragma unroll
    for (int r = 0; r < 4; r++)
      gload_lds16(xb + (size_t)trow[r] * 1024 + k0 + sw8, As_ + ((w << 2) + r) * 512);
    int fr = (w << 3) + (L >> 3);          // 0..31
    size_t go = (size_t)(nb + fr) * 1024 + k0 + sw8;
    gload_lds16(wgp_ + go, Bg_ + w * 512);
    gload_lds16(wup_ + go, Bu_ + w * 512);
  };
  auto compute = [&](const unsigned short* As_, const unsigned short* Bg_,
                     const unsigned short* Bu_) {
    #pragma unroll
    for (int s = 0; s < 2; s++) {
      bf16x8 a[4], bg, bu;
      int ch = (s << 2) + quad;           // logical 16B chunk 0..7
      int po = ((ch ^ l7) << 3);          // physical element offset in row
      #pragma unroll
      for (int mt = 0; mt < 4; mt++)
        a[mt] = *(const bf16x8*)(As_ + (((wr << 6) + (mt << 4) + lane15) << 6) + po);
      int rrow = ((wc << 4) + lane15) << 6;
      bg = *(const bf16x8*)(Bg_ + rrow + po);
      bu = *(const bf16x8*)(Bu_ + rrow + po);
      #pragma unroll
      for (int mt = 0; mt < 4; mt++) {
        accg[mt] = __builtin_amdgcn_mfma_f32_16x16x32_bf16(a[mt], bg, accg[mt], 0, 0, 0);
        accu[mt] = __builtin_amdgcn_mfma_f32_16x16x32_bf16(a[mt], bu, accu[mt], 0, 0, 0);
      }
    }
  };
  stage(As0, Bg0, Bu0, 0);
  __syncthreads();
  for (int it2 = 0; it2 < 8; it2++) {
    int itA = it2 << 1;
    if (itA + 1 < 16) stage(As1, Bg1, Bu1, itA + 1);
    compute(As0, Bg0, Bu0);
    __syncthreads();
    if (itA + 2 < 16) stage(As0, Bg0, Bu0, itA + 2);
    compute(As1, Bg1, Bu1);
    __syncthreads();
  }
  #pragma unroll
  for (int mt = 0; mt < 4; mt++)
    #pragma unroll
    for (int g = 0; g < 4; g++) {
      int r = (wr << 6) + (mt << 4) + (quad << 2) + g;
      if (rb + r < Ne) {
        float gv = accg[mt][g], uv = accu[mt][g];
        float av = gv / (1.f + __expf(-gv)) * uv;
        int f = nb + (wc << 4) + lane15;
        actb[(size_t)(e * CAP + rb + r) * 1024 + f] = f2bf(av);
      }
    }
}

// ---------------- GEMM2: y[slot] = act @ Wd, plain f32 stores ----------------
// De-atomicized (R3). Tile 64(M) x 128(N), BK=64, 16 iters, 2-phase dbuf.
__global__ __launch_bounds__(256, 3) void k_gemm2(
    const unsigned short* __restrict__ actb, const unsigned short* __restrict__ wB,
    const int* __restrict__ counts, float* __restrict__ y) {
  int lin = blockIdx.x;
  int e = lin >> 8;
  int r8 = lin & 255;
  int nbi = r8 & 7;                        // same nb -> same lin%8 -> same XCD
  int mi  = r8 >> 3;                       // 0..31
  int Ne = (e == 8) ? TTOK : counts[e << 4];
  int rb = mi << 6;
  if (rb >= Ne) return;
  int nb = nbi << 7;
  int yb = (e < 8) ? (e << 10) : 8192;     // expert cap 1024 rows, shared 2048
  const unsigned short* wd = wB + (size_t)(18 + e) * MSZ;  // [H][F] bf16
  __shared__ __align__(16) unsigned short As0[64 * 64];
  __shared__ __align__(16) unsigned short As1[64 * 64];
  __shared__ __align__(16) unsigned short Bs0[128 * 64];
  __shared__ __align__(16) unsigned short Bs1[128 * 64];
  int tid = threadIdx.x;
  int w = tid >> 6, L = tid & 63;
  int quad = L >> 4, lane15 = L & 15;
  int l7 = lane15 & 7;
  int sw8 = ((L & 7) ^ (L >> 3)) << 3;
  const unsigned short* arow = actb + (size_t)(e * CAP + rb) * 1024;
  f32x4 acc[4][2];
  #pragma unroll
  for (int mt = 0; mt < 4; mt++)
    #pragma unroll
    for (int nt = 0; nt < 2; nt++) acc[mt][nt] = (f32x4){0.f, 0.f, 0.f, 0.f};
  auto stage = [&](unsigned short* As_, unsigned short* Bs_, int it) {
    int k0 = it << 6;
    #pragma unroll
    for (int r = 0; r < 2; r++) {
      int row = (w << 4) + (r << 3) + (L >> 3);          // 0..63
      gload_lds16(arow + (size_t)row * 1024 + k0 + sw8, As_ + ((w << 1) + r) * 512);
    }
    #pragma unroll
    for (int r = 0; r < 4; r++) {
      int row = (w << 5) + (r << 3) + (L >> 3);          // 0..127
      gload_lds16(wd + (size_t)(nb + row) * 1024 + k0 + sw8, Bs_ + ((w << 2) + r) * 512);
    }
  };
  auto compute = [&](const unsigned short* As_, const unsigned short* Bs_) {
    #pragma unroll
    for (int s = 0; s < 2; s++) {
      bf16x8 a[4], b[2];
      int ch = (s << 2) + quad;
      int po = ((ch ^ l7) << 3);
      #pragma unroll
      for (int mt = 0; mt < 4; mt++)
        a[mt] = *(const bf16x8*)(As_ + (((mt << 4) + lane15) << 6) + po);
      #pragma unroll
      for (int nt = 0; nt < 2; nt++)
        b[nt] = *(const bf16x8*)(Bs_ + (((w << 5) + (nt << 4) + lane15) << 6) + po);
      #pragma unroll
      for (int mt = 0; mt < 4; mt++)
        #pragma unroll
        for (int nt = 0; nt < 2; nt++)
          acc[mt][nt] = __builtin_amdgcn_mfma_f32_16x16x32_bf16(a[mt], b[nt], acc[mt][nt], 0, 0, 0);
    }
  };
  stage(As0, Bs0, 0);
  __syncthreads();
  for (int it2 = 0; it2 < 8; it2++) {
    int itA = it2 << 1;
    if (itA + 1 < 16) stage(As1, Bs1, itA + 1);
    compute(As0, Bs0);
    __syncthreads();
    if (itA + 2 < 16) stage(As0, Bs0, itA + 2);
    compute(As1, Bs1);
    __syncthreads();
  }
  #pragma unroll
  for (int mt = 0; mt < 4; mt++)
    #pragma unroll
    for (int nt = 0; nt < 2; nt++)
      #pragma unroll
      for (int g = 0; g < 4; g++) {
        int r = (mt << 4) + (quad << 2) + g;             // 0..63
        if (rb + r < Ne) {
          int hc = nb + (w << 5) + (nt << 4) + lane15;
          y[(size_t)(yb + rb + r) * 1024 + hc] = acc[mt][nt][g];
        }
      }
}

// ---------------- k_comb: out[t] = w0*y[s0] + w1*y[s1] + y[shared] -----------
__global__ __launch_bounds__(256) void k_comb(
    const float* __restrict__ y, const int2* __restrict__ tsl,
    const float* __restrict__ tw, float* __restrict__ out) {
  int t = blockIdx.x, tid = threadIdx.x;
  int2 s = tsl[t];
  float w0 = tw[t], w1 = 1.f - w0;
  const float4* y4 = (const float4*)y;
  float4 a = y4[(size_t)s.x * 256 + tid];
  float4 b = y4[(size_t)s.y * 256 + tid];
  float4 c = y4[(size_t)(8192 + t) * 256 + tid];
  float4 o;
  o.x = w0 * a.x + w1 * b.x + c.x;
  o.y = w0 * a.y + w1 * b.y + c.y;
  o.z = w0 * a.z + w1 * b.z + c.z;
  o.w = w0 * a.w + w1 * b.w + c.w;
  ((float4*)out)[(size_t)t * 256 + tid] = o;
}

extern "C" void kernel_launch(void* const* d_in, const int* in_sizes, int n_in,
                              void* d_out, int out_size, void* d_ws, size_t ws_size,
                              hipStream_t stream) {
  (void)in_sizes; (void)n_in; (void)ws_size; (void)out_size;
  const float* x   = (const float*)d_in[0];
  const float* wg  = (const float*)d_in[1];
  const float* wgp = (const float*)d_in[2];
  const float* wup = (const float*)d_in[3];
  const float* wdp = (const float*)d_in[4];
  const float* wsg = (const float*)d_in[5];
  const float* wsu = (const float*)d_in[6];
  const float* wsd = (const float*)d_in[7];
  float* out = (float*)d_out;
  char* ws = (char*)d_ws;
  // ws layout (bytes):
  //   wB     @ 0          56623104  (27 x 1M bf16, transposed weights)
  //   xb     @ 56623104    4194304  (x bf16)
  //   actb   @ 60817408   37748736  (act bf16, CAP-strided)
  //   y      @ 98566144   41943040  (10240 rows x 1024 f32 partials)
  //   tok_id @ 140509184     73728
  //   tok_w  @ 140582912     73728
  //   tsl    @ 140656640     16384  (int2 per token)
  //   tw     @ 140673024      8192
  //   counts @ 140681216       576  (padded: counts[e<<4], 64B/line)
  unsigned short* wB   = (unsigned short*)ws;
  unsigned short* xb   = (unsigned short*)(ws + 56623104);
  unsigned short* actb = (unsigned short*)(ws + 60817408);
  float* y      = (float*)(ws + 98566144);
  int*   tok_id = (int*)(ws + 140509184);
  float* tok_w  = (float*)(ws + 140582912);
  int2*  tsl    = (int2*)(ws + 140656640);
  float* tw     = (float*)(ws + 140673024);
  int*   counts = (int*)(ws + 140681216);

  hipMemsetAsync(counts, 0, 576, stream);
  k_prep<<<4992, 256, 0, stream>>>(x, wg, wgp, wsg, wup, wsu, wdp, wsd,
                                   wB, xb, counts, tok_id, tok_w, tsl, tw);
  k_gemm1<<<4608, 256, 0, stream>>>(xb, wB, counts, tok_id, actb);
  k_gemm2<<<2304, 256, 0, stream>>>(actb, wB, counts, y);
  k_comb<<<2048, 256, 0, stream>>>(y, tsl, tw, out);
}

// Round 7
// 243.505 us; speedup vs baseline: 1.0092x; 1.0092x over previous
//
#include <hip/hip_runtime.h>
#include <hip/hip_bf16.h>
#include <stdint.h>

#define HDIM 1024
#define FDIM 1024
#define TTOK 2048
#define CAP  2048
#define MSZ  (1024*1024)

typedef __attribute__((ext_vector_type(8))) __bf16 bf16x8;
typedef __attribute__((ext_vector_type(4))) float  f32x4;

static __device__ __forceinline__ unsigned short f2bf(float v) {
  unsigned int u = __float_as_uint(v);
  u += 0x7FFF + ((u >> 16) & 1);   // RNE
  return (unsigned short)(u >> 16);
}

static __device__ __forceinline__ unsigned pk2(float a, float b) {
  return (unsigned)f2bf(a) | ((unsigned)f2bf(b) << 16);
}

static __device__ __forceinline__ void gload_lds16(const void* g, void* l) {
  __builtin_amdgcn_global_load_lds(
      (const __attribute__((address_space(1))) unsigned int*)g,
      (__attribute__((address_space(3))) unsigned int*)l, 16, 0, 0);
}

// counts PADDED: counts[e<<4] (one 64B line per counter; unpadded = 4096
// serialized same-line RMWs ~35us, fixed in R4).

// Transpose tile body (128 src rows x 64 src cols, 16KB LDS), shared by
// k_prep (Wg/Wu/shared) and k_gemm1's hidden Wd blocks.
// LDS [128 rows][16 slots of 8B], phys_slot = (slot + 2*(row>>3)) & 15.
static __device__ __forceinline__ void tr_tile(
    const float* __restrict__ src, unsigned short* __restrict__ dst,
    unsigned short* T, int rb, int cb, int tid) {
  #pragma unroll
  for (int i = 0; i < 8; i++) {
    int g = tid + (i << 8);          // float4 index 0..2047
    int r = g >> 4;                  // src row 0..127 (16 f4 per row)
    int f4 = g & 15;                 // 16B chunk in row
    float4 v = *(const float4*)(src + (size_t)(rb + r) * 1024 + cb + (f4 << 2));
    uint2 p;
    p.x = pk2(v.x, v.y);
    p.y = pk2(v.z, v.w);
    int ps = (f4 + ((r >> 3) << 1)) & 15;   // rotated 8B slot
    *(uint2*)(T + r * 64 + (ps << 2)) = p;
  }
  __syncthreads();
  int L = tid & 63, w = tid >> 6;
  int q = L & 15;                    // src-row group (dst 16B chunk)
  int cbase = (w << 2) + (L >> 4);   // dst row low bits
  #pragma unroll
  for (int j = 0; j < 4; j++) {
    int c = cbase + (j << 4);        // src col = dst row, 0..63
    int ps = ((c >> 2) + (q << 1)) & 15;
    const unsigned short* p = T + (q << 3) * 64 + (ps << 2) + (c & 3);
    unsigned short u0 = p[0],      u1 = p[64],      u2 = p[2 * 64],
                   u3 = p[3 * 64], u4 = p[4 * 64],  u5 = p[5 * 64],
                   u6 = p[6 * 64], u7 = p[7 * 64];
    uint4 o;
    o.x = (unsigned)u0 | ((unsigned)u1 << 16);
    o.y = (unsigned)u2 | ((unsigned)u3 << 16);
    o.z = (unsigned)u4 | ((unsigned)u5 << 16);
    o.w = (unsigned)u6 | ((unsigned)u7 << 16);
    *(uint4*)(dst + (size_t)(cb + c) * 1024 + rb + (q << 3)) = o;
  }
}

// ---------------- k_prep: router + x-cvt + Wg/Wu transpose -------------------
// blocks 0..511: router; 512..1535: x cvt; 1536..3839: transpose (18 mats).
// Wd transposition moved into the k_gemm1 dispatch (gemm1 doesn't need Wd;
// it hides under gemm1's shadow and gemm2 only starts after that dispatch).
__global__ __launch_bounds__(256) void k_prep(
    const float* __restrict__ x, const float* __restrict__ wg,
    const float* __restrict__ wgp, const float* __restrict__ wsg,
    const float* __restrict__ wup, const float* __restrict__ wsu,
    unsigned short* __restrict__ wB, unsigned short* __restrict__ xb,
    int* __restrict__ counts, int* __restrict__ tok_id, float* __restrict__ tok_w,
    int2* __restrict__ tsl, float* __restrict__ tw) {
  int b = blockIdx.x;
  int tid = threadIdx.x;
  __shared__ __align__(16) unsigned short T[128 * 64];   // 16 KiB
  if (b < 512) {
    // ---- router: wave per token, fp32, top2 + softmax + compaction ----
    int t = (b << 2) + (tid >> 6);
    int L = tid & 63;
    const float* xr = x + (size_t)t * HDIM;
    float acc[8] = {0, 0, 0, 0, 0, 0, 0, 0};
    for (int h = L; h < HDIM; h += 64) {
      float xv = xr[h];
      const float* wr = wg + h * 8;
      #pragma unroll
      for (int e = 0; e < 8; e++) acc[e] += xv * wr[e];
    }
    #pragma unroll
    for (int e = 0; e < 8; e++) {
      float v = acc[e];
      for (int off = 32; off > 0; off >>= 1) v += __shfl_xor(v, off);
      acc[e] = v;
    }
    if (L == 0) {
      int i1 = 0; float v1 = acc[0];
      #pragma unroll
      for (int e = 1; e < 8; e++) if (acc[e] > v1) { v1 = acc[e]; i1 = e; }
      int i2 = -1; float v2 = -1e30f;
      #pragma unroll
      for (int e = 0; e < 8; e++) if (e != i1 && acc[e] > v2) { v2 = acc[e]; i2 = e; }
      float ex = __expf(v2 - v1);
      float w1 = 1.f / (1.f + ex);
      float w2 = 1.f - w1;
      int p1 = atomicAdd(&counts[i1 << 4], 1);   // padded: 1 line per counter
      tok_id[i1 * CAP + p1] = t; tok_w[i1 * CAP + p1] = w1;
      int p2 = atomicAdd(&counts[i2 << 4], 1);
      tok_id[i2 * CAP + p2] = t; tok_w[i2 * CAP + p2] = w2;
      tsl[t] = make_int2((i1 << 10) + p1, (i2 << 10) + p2);  // y-row slots
      tw[t] = w1;
    }
  } else if (b < 1536) {
    // ---- x fp32 -> bf16 (8 elems/thread) ----
    int i = (b - 512) * 256 + tid;
    const float4* in4 = (const float4*)x;
    float4 f0 = in4[i * 2], f1 = in4[i * 2 + 1];
    uint4 v;
    v.x = pk2(f0.x, f0.y); v.y = pk2(f0.z, f0.w);
    v.z = pk2(f1.x, f1.y); v.w = pk2(f1.z, f1.w);
    *((uint4*)(xb + (size_t)i * 8)) = v;
    if (i < TTOK) { tok_id[8 * CAP + i] = i; tok_w[8 * CAP + i] = 1.0f; }
    if (i == 0) counts[8 << 4] = TTOK;
  } else {
    // ---- Wg/Wu transpose + fp32->bf16, tile 128r x 64c ----
    int bt = b - 1536;                 // 0..2303
    int m = bt >> 7;                   // 0..17
    int idx = bt & 127;
    int rb = (idx >> 4) << 7;          // src row base (128 rows)
    int cb = (idx & 15) << 6;          // src col base (64 cols)
    const float* src;
    if (m < 8)       src = wgp + (size_t)m * MSZ;
    else if (m == 8) src = wsg;
    else if (m < 17) src = wup + (size_t)(m - 9) * MSZ;
    else             src = wsu;
    tr_tile(src, wB + (size_t)m * MSZ, T, rb, cb, tid);
  }
}

// LDS tile layout (both GEMMs): row-major [row][64 bf16]; 16B chunk c of row R
// holds logical chunk c ^ (R&7) (conflict-free, verified earlier).
// 1D grids decoded so blocks sharing a B-tile have equal lin%8 -> same XCD.
// Both GEMMs 2-PHASE double-buffered; buffers statically named (rule #20).

// ---------------- GEMM1 (+ hidden Wd transpose blocks) -----------------------
// blocks 0..1151: Wd transpose tiles (reuse As0 as the 16KB staging buffer) —
//   they run concurrently with gemm1, hidden under its shadow; gemm2 (the only
//   consumer of Wd) launches after this dispatch drains.
// blocks 1152..3455: gemm1, tile 128(M) x 64(N per output), BK=64; 4 waves 2x2;
//   g and u share A (R5 shape: 32 MFMA : 8 stage per K-step).
__global__ __launch_bounds__(256, 2) void k_gemm1(
    const unsigned short* __restrict__ xb, unsigned short* __restrict__ wB,
    const float* __restrict__ wdp, const float* __restrict__ wsd,
    const int* __restrict__ counts, const int* __restrict__ tok_id,
    unsigned short* __restrict__ actb) {
  __shared__ __align__(16) unsigned short As0[128 * 64];
  __shared__ __align__(16) unsigned short As1[128 * 64];
  __shared__ __align__(16) unsigned short Bg0[64 * 64];
  __shared__ __align__(16) unsigned short Bg1[64 * 64];
  __shared__ __align__(16) unsigned short Bu0[64 * 64];
  __shared__ __align__(16) unsigned short Bu1[64 * 64];
  int tid = threadIdx.x;
  if (blockIdx.x < 1152) {
    int bt = blockIdx.x;
    int m = bt >> 7;                   // 0..8
    int idx = bt & 127;
    int rb = (idx >> 4) << 7;
    int cb = (idx & 15) << 6;
    const float* src = (m < 8) ? wdp + (size_t)m * MSZ : wsd;
    tr_tile(src, wB + (size_t)(18 + m) * MSZ, As0, rb, cb, tid);
    return;
  }
  int lin = blockIdx.x - 1152;             // 1152 % 8 == 0: mod-8 class kept
  int e = lin >> 8;
  int r9 = lin & 255;
  int nbi = (r9 & 7) | ((r9 >> 7) << 3);   // 0..15, constant mod-8 class per nb
  int mi  = (r9 >> 3) & 15;                // 0..15
  int Ne = (e == 8) ? TTOK : counts[e << 4];
  int rb = mi << 7;
  if (rb >= Ne) return;
  int nb = nbi << 6;
  const unsigned short* wgp_ = wB + (size_t)e * MSZ;        // [F][H] bf16
  const unsigned short* wup_ = wB + (size_t)(9 + e) * MSZ;  // [F][H] bf16
  int w = tid >> 6, L = tid & 63;
  int quad = L >> 4, lane15 = L & 15;
  int wr = w >> 1, wc = w & 1;
  int l7 = lane15 & 7;
  int sw8 = ((L & 7) ^ (L >> 3)) << 3;    // swizzled global chunk offset (elems)
  const int* tlist = tok_id + e * CAP + rb;
  int trow[4];
  #pragma unroll
  for (int r = 0; r < 4; r++) {
    int row = (w << 5) + (r << 3) + (L >> 3);
    trow[r] = (rb + row < Ne) ? tlist[row] : 0;
  }
  f32x4 accg[4][2], accu[4][2];
  #pragma unroll
  for (int mt = 0; mt < 4; mt++)
    #pragma unroll
    for (int nt = 0; nt < 2; nt++) {
      accg[mt][nt] = (f32x4){0.f, 0.f, 0.f, 0.f};
      accu[mt][nt] = (f32x4){0.f, 0.f, 0.f, 0.f};
    }
  auto stage = [&](unsigned short* As_, unsigned short* Bg_, unsigned short* Bu_,
                   int it) {
    int k0 = it << 6;
    #pragma unroll
    for (int r = 0; r < 4; r++)
      gload_lds16(xb + (size_t)trow[r] * 1024 + k0 + sw8, As_ + ((w << 2) + r) * 512);
    #pragma unroll
    for (int r = 0; r < 2; r++) {
      int fr = (((w << 1) + r) << 3) + (L >> 3);
      size_t go = (size_t)(nb + fr) * 1024 + k0 + sw8;
      gload_lds16(wgp_ + go, Bg_ + ((w << 1) + r) * 512);
      gload_lds16(wup_ + go, Bu_ + ((w << 1) + r) * 512);
    }
  };
  auto compute = [&](const unsigned short* As_, const unsigned short* Bg_,
                     const unsigned short* Bu_) {
    #pragma unroll
    for (int s = 0; s < 2; s++) {
      bf16x8 a[4], bg[2], bu[2];
      int ch = (s << 2) + quad;           // logical 16B chunk 0..7
      int po = ((ch ^ l7) << 3);          // physical element offset in row
      #pragma unroll
      for (int mt = 0; mt < 4; mt++)
        a[mt] = *(const bf16x8*)(As_ + (((wr << 6) + (mt << 4) + lane15) << 6) + po);
      #pragma unroll
      for (int nt = 0; nt < 2; nt++) {
        int rrow = ((wc << 5) + (nt << 4) + lane15) << 6;
        bg[nt] = *(const bf16x8*)(Bg_ + rrow + po);
        bu[nt] = *(const bf16x8*)(Bu_ + rrow + po);
      }
      #pragma unroll
      for (int mt = 0; mt < 4; mt++)
        #pragma unroll
        for (int nt = 0; nt < 2; nt++) {
          accg[mt][nt] = __builtin_amdgcn_mfma_f32_16x16x32_bf16(a[mt], bg[nt], accg[mt][nt], 0, 0, 0);
          accu[mt][nt] = __builtin_amdgcn_mfma_f32_16x16x32_bf16(a[mt], bu[nt], accu[mt][nt], 0, 0, 0);
        }
    }
  };
  stage(As0, Bg0, Bu0, 0);
  __syncthreads();
  for (int it2 = 0; it2 < 8; it2++) {
    int itA = it2 << 1;
    if (itA + 1 < 16) stage(As1, Bg1, Bu1, itA + 1);
    compute(As0, Bg0, Bu0);
    __syncthreads();
    if (itA + 2 < 16) stage(As0, Bg0, Bu0, itA + 2);
    compute(As1, Bg1, Bu1);
    __syncthreads();
  }
  #pragma unroll
  for (int mt = 0; mt < 4; mt++)
    #pragma unroll
    for (int nt = 0; nt < 2; nt++)
      #pragma unroll
      for (int g = 0; g < 4; g++) {
        int r = (wr << 6) + (mt << 4) + (quad << 2) + g;
        if (rb + r < Ne) {
          float gv = accg[mt][nt][g], uv = accu[mt][nt][g];
          float av = gv / (1.f + __expf(-gv)) * uv;
          int f = nb + (wc << 5) + (nt << 4) + lane15;
          actb[(size_t)(e * CAP + rb + r) * 1024 + f] = f2bf(av);
        }
      }
}

// ---------------- GEMM2: y[slot] = act @ Wd, plain f32 stores ----------------
// De-atomicized (R3). Tile 64(M) x 128(N), BK=64, 16 iters, 2-phase dbuf.
__global__ __launch_bounds__(256, 3) void k_gemm2(
    const unsigned short* __restrict__ actb, const unsigned short* __restrict__ wB,
    const int* __restrict__ counts, float* __restrict__ y) {
  int lin = blockIdx.x;
  int e = lin >> 8;
  int r8 = lin & 255;
  int nbi = r8 & 7;                        // same nb -> same lin%8 -> same XCD
  int mi  = r8 >> 3;                       // 0..31
  int Ne = (e == 8) ? TTOK : counts[e << 4];
  int rb = mi << 6;
  if (rb >= Ne) return;
  int nb = nbi << 7;
  int yb = (e < 8) ? (e << 10) : 8192;     // expert cap 1024 rows, shared 2048
  const unsigned short* wd = wB + (size_t)(18 + e) * MSZ;  // [H][F] bf16
  __shared__ __align__(16) unsigned short As0[64 * 64];
  __shared__ __align__(16) unsigned short As1[64 * 64];
  __shared__ __align__(16) unsigned short Bs0[128 * 64];
  __shared__ __align__(16) unsigned short Bs1[128 * 64];
  int tid = threadIdx.x;
  int w = tid >> 6, L = tid & 63;
  int quad = L >> 4, lane15 = L & 15;
  int l7 = lane15 & 7;
  int sw8 = ((L & 7) ^ (L >> 3)) << 3;
  const unsigned short* arow = actb + (size_t)(e * CAP + rb) * 1024;
  f32x4 acc[4][2];
  #pragma unroll
  for (int mt = 0; mt < 4; mt++)
    #pragma unroll
    for (int nt = 0; nt < 2; nt++) acc[mt][nt] = (f32x4){0.f, 0.f, 0.f, 0.f};
  auto stage = [&](unsigned short* As_, unsigned short* Bs_, int it) {
    int k0 = it << 6;
    #pragma unroll
    for (int r = 0; r < 2; r++) {
      int row = (w << 4) + (r << 3) + (L >> 3);          // 0..63
      gload_lds16(arow + (size_t)row * 1024 + k0 + sw8, As_ + ((w << 1) + r) * 512);
    }
    #pragma unroll
    for (int r = 0; r < 4; r++) {
      int row = (w << 5) + (r << 3) + (L >> 3);          // 0..127
      gload_lds16(wd + (size_t)(nb + row) * 1024 + k0 + sw8, Bs_ + ((w << 2) + r) * 512);
    }
  };
  auto compute = [&](const unsigned short* As_, const unsigned short* Bs_) {
    #pragma unroll
    for (int s = 0; s < 2; s++) {
      bf16x8 a[4], b[2];
      int ch = (s << 2) + quad;
      int po = ((ch ^ l7) << 3);
      #pragma unroll
      for (int mt = 0; mt < 4; mt++)
        a[mt] = *(const bf16x8*)(As_ + (((mt << 4) + lane15) << 6) + po);
      #pragma unroll
      for (int nt = 0; nt < 2; nt++)
        b[nt] = *(const bf16x8*)(Bs_ + (((w << 5) + (nt << 4) + lane15) << 6) + po);
      #pragma unroll
      for (int mt = 0; mt < 4; mt++)
        #pragma unroll
        for (int nt = 0; nt < 2; nt++)
          acc[mt][nt] = __builtin_amdgcn_mfma_f32_16x16x32_bf16(a[mt], b[nt], acc[mt][nt], 0, 0, 0);
    }
  };
  stage(As0, Bs0, 0);
  __syncthreads();
  for (int it2 = 0; it2 < 8; it2++) {
    int itA = it2 << 1;
    if (itA + 1 < 16) stage(As1, Bs1, itA + 1);
    compute(As0, Bs0);
    __syncthreads();
    if (itA + 2 < 16) stage(As0, Bs0, itA + 2);
    compute(As1, Bs1);
    __syncthreads();
  }
  #pragma unroll
  for (int mt = 0; mt < 4; mt++)
    #pragma unroll
    for (int nt = 0; nt < 2; nt++)
      #pragma unroll
      for (int g = 0; g < 4; g++) {
        int r = (mt << 4) + (quad << 2) + g;             // 0..63
        if (rb + r < Ne) {
          int hc = nb + (w << 5) + (nt << 4) + lane15;
          y[(size_t)(yb + rb + r) * 1024 + hc] = acc[mt][nt][g];
        }
      }
}

// ---------------- k_comb: out[t] = w0*y[s0] + w1*y[s1] + y[shared] -----------
__global__ __launch_bounds__(256) void k_comb(
    const float* __restrict__ y, const int2* __restrict__ tsl,
    const float* __restrict__ tw, float* __restrict__ out) {
  int t = blockIdx.x, tid = threadIdx.x;
  int2 s = tsl[t];
  float w0 = tw[t], w1 = 1.f - w0;
  const float4* y4 = (const float4*)y;
  float4 a = y4[(size_t)s.x * 256 + tid];
  float4 b = y4[(size_t)s.y * 256 + tid];
  float4 c = y4[(size_t)(8192 + t) * 256 + tid];
  float4 o;
  o.x = w0 * a.x + w1 * b.x + c.x;
  o.y = w0 * a.y + w1 * b.y + c.y;
  o.z = w0 * a.z + w1 * b.z + c.z;
  o.w = w0 * a.w + w1 * b.w + c.w;
  ((float4*)out)[(size_t)t * 256 + tid] = o;
}

extern "C" void kernel_launch(void* const* d_in, const int* in_sizes, int n_in,
                              void* d_out, int out_size, void* d_ws, size_t ws_size,
                              hipStream_t stream) {
  (void)in_sizes; (void)n_in; (void)ws_size; (void)out_size;
  const float* x   = (const float*)d_in[0];
  const float* wg  = (const float*)d_in[1];
  const float* wgp = (const float*)d_in[2];
  const float* wup = (const float*)d_in[3];
  const float* wdp = (const float*)d_in[4];
  const float* wsg = (const float*)d_in[5];
  const float* wsu = (const float*)d_in[6];
  const float* wsd = (const float*)d_in[7];
  float* out = (float*)d_out;
  char* ws = (char*)d_ws;
  // ws layout (bytes):
  //   wB     @ 0          56623104  (27 x 1M bf16, transposed weights)
  //   xb     @ 56623104    4194304  (x bf16)
  //   actb   @ 60817408   37748736  (act bf16, CAP-strided)
  //   y      @ 98566144   41943040  (10240 rows x 1024 f32 partials)
  //   tok_id @ 140509184     73728
  //   tok_w  @ 140582912     73728
  //   tsl    @ 140656640     16384  (int2 per token)
  //   tw     @ 140673024      8192
  //   counts @ 140681216       576  (padded: counts[e<<4], 64B/line)
  unsigned short* wB   = (unsigned short*)ws;
  unsigned short* xb   = (unsigned short*)(ws + 56623104);
  unsigned short* actb = (unsigned short*)(ws + 60817408);
  float* y      = (float*)(ws + 98566144);
  int*   tok_id = (int*)(ws + 140509184);
  float* tok_w  = (float*)(ws + 140582912);
  int2*  tsl    = (int2*)(ws + 140656640);
  float* tw     = (float*)(ws + 140673024);
  int*   counts = (int*)(ws + 140681216);

  hipMemsetAsync(counts, 0, 576, stream);
  k_prep<<<3840, 256, 0, stream>>>(x, wg, wgp, wsg, wup, wsu,
                                   wB, xb, counts, tok_id, tok_w, tsl, tw);
  k_gemm1<<<3456, 256, 0, stream>>>(xb, wB, wdp, wsd, counts, tok_id, actb);
  k_gemm2<<<2304, 256, 0, stream>>>(actb, wB, counts, y);
  k_comb<<<2048, 256, 0, stream>>>(y, tsl, tw, out);
}